// Round 12
// baseline (339.955 us; speedup 1.0000x reference)
//
#include <hip/hip_runtime.h>
#include <hip/hip_fp16.h>

#define NN 50000
#define NP 25000
#define NE 800000
#define DD 64
#define NL 4
#define CSR_CAP (NE + 7 * NN + 64)   // padded segments + prefetch slack

// ---- helpers ------------------------------------------------------------

__device__ __forceinline__ ushort f2bf(float f) {
    unsigned u = __float_as_uint(f);
    unsigned r = (u + 0x7fffu + ((u >> 16) & 1u)) >> 16;   // RNE
    return (ushort)r;
}

__device__ __forceinline__ float4 bf4_to_f4(uint a, uint b) {
    float4 r;
    r.x = __uint_as_float(a << 16);
    r.y = __uint_as_float(a & 0xffff0000u);
    r.z = __uint_as_float(b << 16);
    r.w = __uint_as_float(b & 0xffff0000u);
    return r;
}

__device__ __forceinline__ float4 ld_bf16x4(const uint2* p) {
    uint2 q = *p;
    return bf4_to_f4(q.x, q.y);
}

// ---- CSR build ----------------------------------------------------------
// Pass 1: count in-degree AND record each edge's rank within its dst bucket.

__global__ void count_edges_k(const int* __restrict__ dst, int* __restrict__ cnt,
                              int* __restrict__ rank, int E) {
    int e = blockIdx.x * 256 + threadIdx.x;
    if (e < E) rank[e] = atomicAdd(&cnt[dst[e]], 1);
}

// Block-local exclusive scan of PADDED counts (multiple of 8 per segment).
// Consumers add bsum[i>>10] to get the global offset (no finalize pass).
// Also computes dinv (depends only on cnt).
__global__ void scan_local_k(const int* __restrict__ cnt, int* __restrict__ rowptr,
                             int* __restrict__ bsum, float* __restrict__ dinv, int n) {
    __shared__ int tmp[1024];
    int t = threadIdx.x;
    int i = blockIdx.x * 1024 + t;
    int c = (i < n) ? cnt[i] : 0;
    int v = (i < n) ? ((c + 7) & ~7) : 0;
    tmp[t] = v;
    __syncthreads();
    for (int off = 1; off < 1024; off <<= 1) {
        int a = (t >= off) ? tmp[t - off] : 0;
        __syncthreads();
        tmp[t] += a;
        __syncthreads();
    }
    if (i < n) {
        rowptr[i] = tmp[t] - v;      // block-local exclusive
        dinv[i] = rsqrtf((float)(c + 1));   // +1 self loop
        if (i == n - 1) rowptr[n] = tmp[t];  // block-local inclusive total
    }
    if (t == 1023) bsum[blockIdx.x] = tmp[1023];
}

__global__ void scan_sums_k(int* bsum, int nb) {
    int t = threadIdx.x;                    // 64 threads, nb <= 64
    int v = (t < nb) ? bsum[t] : 0;
    int s = v;
#pragma unroll
    for (int o = 1; o < 64; o <<= 1) {
        int u = __shfl_up(s, o);
        if (t >= o) s += u;
    }
    if (t < nb) bsum[t] = s - v;            // exclusive block bases
}

// csr entry: bits 0..15 = src index (NN < 65536), bits 16..31 = fp16 weight.
// Block range [0,3125): CSR fill (no atomics). [3125,4688): unpool scatter.
__global__ void fill_scatter_k(const int* __restrict__ src, const int* __restrict__ dst,
                               const int* __restrict__ rank, const int* __restrict__ rowptr,
                               const int* __restrict__ bsum,
                               const float* __restrict__ dinv, uint* __restrict__ csr,
                               const float4* __restrict__ x4, const int* __restrict__ idx,
                               ushort4* __restrict__ c0) {
    int b = blockIdx.x;
    if (b < 3125) {
        int e = b * 256 + threadIdx.x;   // 3125*256 == NE
        int s = src[e], d = dst[e];
        int p = rowptr[d] + bsum[d >> 10] + rank[e];
        float w = dinv[s] * dinv[d];
        uint h = (uint)__half_as_ushort(__float2half_rn(w));
        csr[p] = (uint)s | (h << 16);
    } else {
        int i = (b - 3125) * 256 + threadIdx.x;   // NP*16 quads
        if (i >= NP * 16) return;
        int row = i >> 4, q = i & 15;
        float4 v = x4[i];
        ushort4 o;
        o.x = f2bf(v.x); o.y = f2bf(v.y); o.z = f2bf(v.z); o.w = f2bf(v.w);
        c0[(size_t)idx[row] * 16 + q] = o;
    }
}

// ---- GEMM: xw_bf16[50000x64] = cur_bf16[50000x64] @ W[64x64] ------------

__global__ void gemm64_k(const uint2* __restrict__ in2, const float* __restrict__ W,
                         ushort* __restrict__ out) {
    __shared__ float sW[64][64];     // 16 KB
    __shared__ float srow[16][65];   // +1 pad: kills 4-way bank conflict on a
    int t = threadIdx.x;             // 256 threads
    const float4* W4 = (const float4*)W;
    float4* sW4 = (float4*)sW;
#pragma unroll
    for (int j = 0; j < 4; ++j) sW4[t + 256 * j] = W4[t + 256 * j];
    int r0 = blockIdx.x * 16;
    float4 val = ld_bf16x4(in2 + (size_t)r0 * 16 + t);
    *(float4*)&srow[t >> 4][4 * (t & 15)] = val;
    __syncthreads();
    int r = t >> 4;            // 0..15
    int c4 = (t & 15) * 4;     // 0,4,...,60
    float ax = 0.f, ay = 0.f, az = 0.f, aw = 0.f;
#pragma unroll
    for (int k = 0; k < 64; ++k) {
        float a = srow[r][k];
        float4 w = *(const float4*)&sW[k][c4];
        ax += a * w.x; ay += a * w.y; az += a * w.z; aw += a * w.w;
    }
    ushort4 o;
    o.x = f2bf(ax); o.y = f2bf(ay); o.z = f2bf(az); o.w = f2bf(aw);
    *(ushort4*)&out[(size_t)(r0 + r) * 64 + c4] = o;
}

// ---- fused: aggregate(bf16 gather) + bias + LN + LeakyReLU --------------
// 4 nodes per wave, 16 lanes per node = 2 octets. Each octet handles every
// other 8-entry CSR block (A: blocks 0,2,..; B: 1,3,..) -> half the serial
// chain per wave vs 8-lanes/node, and 12500 waves total (occupancy-capped
// at 32/CU instead of grid-limited 24/CU). Lane l8 holds features
// 8*l8..8*l8+7; octet pair combined with one shfl_xor(8).
// Padded CSR (multiple of 8, pads src=0/w=0): no clamps, no tail logic.

__global__ void __launch_bounds__(256, 8)
agg_ln_k(const uint4* __restrict__ xw4, const int* __restrict__ rowptr,
         const int* __restrict__ bsum,
         const uint* __restrict__ csr, const float* __restrict__ dinv,
         const float4* __restrict__ bias4, const float4* __restrict__ gamma4,
         const float4* __restrict__ beta4, uint4* next,
         const uint4* c1, const uint4* c2, const uint4* c3,
         float4* outp, int last) {
    int tid = threadIdx.x;
    int l8 = tid & 7;                       // feature octet-chunk 0..7
    int oct = (tid >> 3) & 1;               // which octet of the pair
    int v = blockIdx.x * 16 + (tid >> 4);   // 16 nodes per 256-thread block
    if (v >= NN) return;
    const uint4* csrq = (const uint4*)csr;
    int jb = rowptr[v] + bsum[v >> 10];
    int je = rowptr[v + 1] + bsum[(v + 1) >> 10];   // both multiples of 8
    float4 aLo = make_float4(0.f, 0.f, 0.f, 0.f);
    float4 aHi = make_float4(0.f, 0.f, 0.f, 0.f);
    if (!oct) {                              // self loop, added once
        float dv = dinv[v];
        uint4 q = xw4[(size_t)v * 8 + l8];
        float4 lo = bf4_to_f4(q.x, q.y), hi = bf4_to_f4(q.z, q.w);
        float s = dv * dv;
        aLo.x = s * lo.x; aLo.y = s * lo.y; aLo.z = s * lo.z; aLo.w = s * lo.w;
        aHi.x = s * hi.x; aHi.y = s * hi.y; aHi.z = s * hi.z; aHi.w = s * hi.w;
    }
#define WGT(E)  __half2float(__ushort_as_half((ushort)((E) >> 16)))
    for (int j = jb + oct * 8; j < je; j += 16) {
        const uint4* cp = csrq + (j >> 2);
        uint4 ca = cp[0], cb = cp[1];
        uint4 q0 = xw4[(size_t)(ca.x & 0xffffu) * 8 + l8];
        uint4 q1 = xw4[(size_t)(ca.y & 0xffffu) * 8 + l8];
        uint4 q2 = xw4[(size_t)(ca.z & 0xffffu) * 8 + l8];
        uint4 q3 = xw4[(size_t)(ca.w & 0xffffu) * 8 + l8];
        uint4 q4 = xw4[(size_t)(cb.x & 0xffffu) * 8 + l8];
        uint4 q5 = xw4[(size_t)(cb.y & 0xffffu) * 8 + l8];
        uint4 q6 = xw4[(size_t)(cb.z & 0xffffu) * 8 + l8];
        uint4 q7 = xw4[(size_t)(cb.w & 0xffffu) * 8 + l8];
        float w0 = WGT(ca.x), w1 = WGT(ca.y), w2 = WGT(ca.z), w3 = WGT(ca.w);
        float w4 = WGT(cb.x), w5 = WGT(cb.y), w6 = WGT(cb.z), w7 = WGT(cb.w);
#define ACC(Q, W) { \
        float4 lo = bf4_to_f4(Q.x, Q.y), hi = bf4_to_f4(Q.z, Q.w); \
        aLo.x += W * lo.x; aLo.y += W * lo.y; aLo.z += W * lo.z; aLo.w += W * lo.w; \
        aHi.x += W * hi.x; aHi.y += W * hi.y; aHi.z += W * hi.z; aHi.w += W * hi.w; }
        ACC(q0, w0) ACC(q1, w1) ACC(q2, w2) ACC(q3, w3)
        ACC(q4, w4) ACC(q5, w5) ACC(q6, w6) ACC(q7, w7)
#undef ACC
    }
#undef WGT
    // combine octet pair (lanes l and l+8 hold the same features)
    aLo.x += __shfl_xor(aLo.x, 8); aLo.y += __shfl_xor(aLo.y, 8);
    aLo.z += __shfl_xor(aLo.z, 8); aLo.w += __shfl_xor(aLo.w, 8);
    aHi.x += __shfl_xor(aHi.x, 8); aHi.y += __shfl_xor(aHi.y, 8);
    aHi.z += __shfl_xor(aHi.z, 8); aHi.w += __shfl_xor(aHi.w, 8);
    float4 bLo = bias4[2 * l8], bBhi = bias4[2 * l8 + 1];
    aLo.x += bLo.x; aLo.y += bLo.y; aLo.z += bLo.z; aLo.w += bLo.w;
    aHi.x += bBhi.x; aHi.y += bBhi.y; aHi.z += bBhi.z; aHi.w += bBhi.w;
    // LayerNorm over 64 features within the 8-lane octet
    float s = aLo.x + aLo.y + aLo.z + aLo.w + aHi.x + aHi.y + aHi.z + aHi.w;
#pragma unroll
    for (int o = 1; o <= 4; o <<= 1) s += __shfl_xor(s, o);
    float mu = s * (1.0f / 64.0f);
    float4 cLo = make_float4(aLo.x - mu, aLo.y - mu, aLo.z - mu, aLo.w - mu);
    float4 cHi = make_float4(aHi.x - mu, aHi.y - mu, aHi.z - mu, aHi.w - mu);
    float q2v = cLo.x * cLo.x + cLo.y * cLo.y + cLo.z * cLo.z + cLo.w * cLo.w
              + cHi.x * cHi.x + cHi.y * cHi.y + cHi.z * cHi.z + cHi.w * cHi.w;
#pragma unroll
    for (int o = 1; o <= 4; o <<= 1) q2v += __shfl_xor(q2v, o);
    float rs = rsqrtf(q2v * (1.0f / 64.0f) + 1e-5f);
    if (oct) return;                        // octet A finishes the epilogue
    float4 gLo = gamma4[2 * l8], gHi = gamma4[2 * l8 + 1];
    float4 tLo = beta4[2 * l8],  tHi = beta4[2 * l8 + 1];
    float4 yLo = make_float4(cLo.x * rs * gLo.x + tLo.x, cLo.y * rs * gLo.y + tLo.y,
                             cLo.z * rs * gLo.z + tLo.z, cLo.w * rs * gLo.w + tLo.w);
    float4 yHi = make_float4(cHi.x * rs * gHi.x + tHi.x, cHi.y * rs * gHi.y + tHi.y,
                             cHi.z * rs * gHi.z + tHi.z, cHi.w * rs * gHi.w + tHi.w);
    float4 eLo = make_float4(yLo.x > 0.f ? yLo.x : 0.01f * yLo.x,
                             yLo.y > 0.f ? yLo.y : 0.01f * yLo.y,
                             yLo.z > 0.f ? yLo.z : 0.01f * yLo.z,
                             yLo.w > 0.f ? yLo.w : 0.01f * yLo.w);
    float4 eHi = make_float4(yHi.x > 0.f ? yHi.x : 0.01f * yHi.x,
                             yHi.y > 0.f ? yHi.y : 0.01f * yHi.y,
                             yHi.z > 0.f ? yHi.z : 0.01f * yHi.z,
                             yHi.w > 0.f ? yHi.w : 0.01f * yHi.w);
    if (!last) {
        uint4 o;
        o.x = (uint)f2bf(eLo.x) | ((uint)f2bf(eLo.y) << 16);
        o.y = (uint)f2bf(eLo.z) | ((uint)f2bf(eLo.w) << 16);
        o.z = (uint)f2bf(eHi.x) | ((uint)f2bf(eHi.y) << 16);
        o.w = (uint)f2bf(eHi.z) | ((uint)f2bf(eHi.w) << 16);
        next[(size_t)v * 8 + l8] = o;
    } else {
        uint4 u1 = c1[(size_t)v * 8 + l8];
        uint4 u2 = c2[(size_t)v * 8 + l8];
        uint4 u3 = c3[(size_t)v * 8 + l8];
        float4 p1 = bf4_to_f4(u1.x, u1.y), p1h = bf4_to_f4(u1.z, u1.w);
        float4 p2 = bf4_to_f4(u2.x, u2.y), p2h = bf4_to_f4(u2.z, u2.w);
        float4 p3 = bf4_to_f4(u3.x, u3.y), p3h = bf4_to_f4(u3.z, u3.w);
        float4 oLo, oHi;
        oLo.x = 0.5f * (p1.x + p2.x + p3.x + eLo.x);
        oLo.y = 0.5f * (p1.y + p2.y + p3.y + eLo.y);
        oLo.z = 0.5f * (p1.z + p2.z + p3.z + eLo.z);
        oLo.w = 0.5f * (p1.w + p2.w + p3.w + eLo.w);
        oHi.x = 0.5f * (p1h.x + p2h.x + p3h.x + eHi.x);
        oHi.y = 0.5f * (p1h.y + p2h.y + p3h.y + eHi.y);
        oHi.z = 0.5f * (p1h.z + p2h.z + p3h.z + eHi.z);
        oHi.w = 0.5f * (p1h.w + p2h.w + p3h.w + eHi.w);
        outp[(size_t)v * 16 + 2 * l8]     = oLo;
        outp[(size_t)v * 16 + 2 * l8 + 1] = oHi;
    }
}

// ---- launch -------------------------------------------------------------

extern "C" void kernel_launch(void* const* d_in, const int* in_sizes, int n_in,
                              void* d_out, int out_size, void* d_ws, size_t ws_size,
                              hipStream_t stream) {
    const float* x      = (const float*)d_in[0];
    const int*   ei     = (const int*)d_in[1];
    const int*   src    = ei;
    const int*   dst    = ei + NE;
    const int*   idx    = (const int*)d_in[2];
    const float* Ws     = (const float*)d_in[3];
    const float* bs     = (const float*)d_in[4];
    const float* gammas = (const float*)d_in[5];
    const float* betas  = (const float*)d_in[6];
    float* out = (float*)d_out;

    char* w = (char*)d_ws;
    auto alloc = [&](size_t bytes) -> char* {
        char* p = w;
        w += (bytes + 255) & ~(size_t)255;
        return p;
    };
    // cnt | csr | c0 contiguous -> single zero-fill
    char*   zbase  = w;
    int*    cnt    = (int*)alloc((size_t)NN * 4);
    uint*   csr    = (uint*)alloc((size_t)CSR_CAP * 4);
    ushort* c0     = (ushort*)alloc((size_t)NN * 64 * 2);
    size_t  zbytes = (size_t)(w - zbase);
    ushort* c[NL];
    c[0] = c0;
    for (int l = 1; l < NL; ++l) c[l] = (ushort*)alloc((size_t)NN * 64 * 2);
    ushort* xw     = (ushort*)alloc((size_t)NN * 64 * 2);
    int*    rowptr = (int*)alloc((size_t)(NN + 1) * 4);
    int*    rank   = (int*)alloc((size_t)NE * 4);
    float*  dinv   = (float*)alloc((size_t)NN * 4);
    int*    bsum   = (int*)alloc(64 * 4);

    hipMemsetAsync(zbase, 0, zbytes, stream);

    count_edges_k<<<(NE + 255) / 256, 256, 0, stream>>>(dst, cnt, rank, NE);
    int nb = (NN + 1023) / 1024;   // 49
    scan_local_k<<<nb, 1024, 0, stream>>>(cnt, rowptr, bsum, dinv, NN);
    scan_sums_k<<<1, 64, 0, stream>>>(bsum, nb);
    fill_scatter_k<<<3125 + 1563, 256, 0, stream>>>(src, dst, rank, rowptr, bsum, dinv,
                                                    csr, (const float4*)x, idx,
                                                    (ushort4*)c[0]);

    int agrid = (NN + 15) / 16;   // 3125
    for (int l = 0; l < NL; ++l) {
        gemm64_k<<<NN / 16, 256, 0, stream>>>((const uint2*)c[l], Ws + (size_t)l * 64 * 64,
                                              xw);
        int last = (l == NL - 1);
        agg_ln_k<<<agrid, 256, 0, stream>>>((const uint4*)xw, rowptr, bsum, csr, dinv,
                                            (const float4*)(bs + l * 64),
                                            (const float4*)(gammas + l * 64),
                                            (const float4*)(betas + l * 64),
                                            last ? nullptr : (uint4*)c[l + 1],
                                            (const uint4*)c[1], (const uint4*)c[2],
                                            (const uint4*)c[3], (float4*)out, last);
    }
}

// Round 13
// 199.999 us; speedup vs baseline: 1.6998x; 1.6998x over previous
//
#include <hip/hip_runtime.h>
#include <hip/hip_fp16.h>

#define NN 50000
#define NP 25000
#define NE 800000
#define DD 64
#define NL 4

// ---- helpers ------------------------------------------------------------

__device__ __forceinline__ ushort f2bf(float f) {
    unsigned u = __float_as_uint(f);
    unsigned r = (u + 0x7fffu + ((u >> 16) & 1u)) >> 16;   // RNE
    return (ushort)r;
}

__device__ __forceinline__ float4 bf4_to_f4(uint a, uint b) {
    float4 r;
    r.x = __uint_as_float(a << 16);
    r.y = __uint_as_float(a & 0xffff0000u);
    r.z = __uint_as_float(b << 16);
    r.w = __uint_as_float(b & 0xffff0000u);
    return r;
}

__device__ __forceinline__ float4 ld_bf16x4(const uint2* p) {
    uint2 q = *p;
    return bf4_to_f4(q.x, q.y);
}

// ---- CSR build ----------------------------------------------------------
// Pass 1: count in-degree AND record each edge's rank within its dst bucket
// (the atomicAdd return). Pass 2 (fill) then needs NO atomics.

__global__ void count_edges_k(const int* __restrict__ dst, int* __restrict__ cnt,
                              int* __restrict__ rank, int E) {
    int e = blockIdx.x * 256 + threadIdx.x;
    if (e < E) rank[e] = atomicAdd(&cnt[dst[e]], 1);
}

__global__ void scan_local_k(const int* __restrict__ cnt, int* __restrict__ rowptr,
                             int* __restrict__ bsum, int n) {
    __shared__ int tmp[1024];
    int t = threadIdx.x;
    int i = blockIdx.x * 1024 + t;
    int v = (i < n) ? cnt[i] : 0;
    tmp[t] = v;
    __syncthreads();
    for (int off = 1; off < 1024; off <<= 1) {
        int a = (t >= off) ? tmp[t - off] : 0;
        __syncthreads();
        tmp[t] += a;
        __syncthreads();
    }
    if (i < n) rowptr[i] = tmp[t] - v;      // block-local exclusive scan
    if (t == 1023) bsum[blockIdx.x] = tmp[1023];
}

// Finalize: each block redundantly wave-scans the 49 raw block sums (cheap),
// adds its base, computes dinv. Drops the separate scan_sums dispatch.
__global__ void finalize_k(int* __restrict__ rowptr, const int* __restrict__ bsum,
                           const int* __restrict__ cnt, float* __restrict__ dinv,
                           int n, int nb) {
    __shared__ int base_sh, total_sh;
    int t = threadIdx.x;
    if (t < 64) {                           // one wave scans the block sums
        int v = (t < nb) ? bsum[t] : 0;
        int s = v;
#pragma unroll
        for (int o = 1; o < 64; o <<= 1) {
            int u = __shfl_up(s, o);
            if (t >= o) s += u;
        }
        if (t == (int)blockIdx.x) base_sh = s - v;   // exclusive base for this block
        if (t == nb - 1) total_sh = s;               // grand total
    }
    __syncthreads();
    int i = blockIdx.x * 1024 + t;
    if (i < n) {
        rowptr[i] += base_sh;
        dinv[i] = rsqrtf((float)(cnt[i] + 1));   // +1 self loop; deg >= 1 always
    }
    if (i == n) rowptr[n] = total_sh;
}

// csr entry: bits 0..15 = src index (NN < 65536), bits 16..31 = fp16 weight.
// Block range [0,3125): CSR fill (no atomics). [3125,4688): unpool scatter.
__global__ void fill_scatter_k(const int* __restrict__ src, const int* __restrict__ dst,
                               const int* __restrict__ rank, const int* __restrict__ rowptr,
                               const float* __restrict__ dinv, uint* __restrict__ csr,
                               const float4* __restrict__ x4, const int* __restrict__ idx,
                               ushort4* __restrict__ c0) {
    int b = blockIdx.x;
    if (b < 3125) {
        int e = b * 256 + threadIdx.x;   // 3125*256 == NE
        int s = src[e], d = dst[e];
        int p = rowptr[d] + rank[e];
        float w = dinv[s] * dinv[d];
        uint h = (uint)__half_as_ushort(__float2half_rn(w));
        csr[p] = (uint)s | (h << 16);
    } else {
        int i = (b - 3125) * 256 + threadIdx.x;   // NP*16 quads
        if (i >= NP * 16) return;
        int row = i >> 4, q = i & 15;
        float4 v = x4[i];
        ushort4 o;
        o.x = f2bf(v.x); o.y = f2bf(v.y); o.z = f2bf(v.z); o.w = f2bf(v.w);
        c0[(size_t)idx[row] * 16 + q] = o;
    }
}

// ---- GEMM: xw_bf16[50000x64] = cur_bf16[50000x64] @ W[64x64] ------------

__global__ void gemm64_k(const uint2* __restrict__ in2, const float* __restrict__ W,
                         ushort* __restrict__ out) {
    __shared__ float sW[64][64];     // 16 KB
    __shared__ float srow[16][64];   // 4 KB
    int t = threadIdx.x;             // 256 threads
    const float4* W4 = (const float4*)W;
    float4* sW4 = (float4*)sW;
#pragma unroll
    for (int j = 0; j < 4; ++j) sW4[t + 256 * j] = W4[t + 256 * j];
    int r0 = blockIdx.x * 16;
    float4 val = ld_bf16x4(in2 + (size_t)r0 * 16 + t);
    *(float4*)&srow[t >> 4][4 * (t & 15)] = val;
    __syncthreads();
    int r = t >> 4;            // 0..15
    int c4 = (t & 15) * 4;     // 0,4,...,60
    float ax = 0.f, ay = 0.f, az = 0.f, aw = 0.f;
#pragma unroll
    for (int k = 0; k < 64; ++k) {
        float a = srow[r][k];
        float4 w = *(const float4*)&sW[k][c4];
        ax += a * w.x; ay += a * w.y; az += a * w.z; aw += a * w.w;
    }
    ushort4 o;
    o.x = f2bf(ax); o.y = f2bf(ay); o.z = f2bf(az); o.w = f2bf(aw);
    *(ushort4*)&out[(size_t)(r0 + r) * 64 + c4] = o;
}

// ---- fused: aggregate(bf16 gather) + bias + LN + LeakyReLU --------------
// R7-proven structure: 8 nodes per wave (8-lane octets). Lane l8 holds
// features 8*l8..8*l8+7 (one uint4 = 8 bf16; 8 lanes cover the 128B row).
// Edge loop 8-deep unrolled (clamped indices, masked weights) -> 64
// row-gathers in flight per wave. No launch_bounds: VGPRs buy MLP here.
// If last!=0: epilogue fuses h = 0.5*(c1+c2+c3+act), writes f32 out.

__global__ void agg_ln_k(const uint4* __restrict__ xw4, const int* __restrict__ rowptr,
                         const uint* __restrict__ csr, const float* __restrict__ dinv,
                         const float4* __restrict__ bias4, const float4* __restrict__ gamma4,
                         const float4* __restrict__ beta4, uint4* next,
                         const uint4* c1, const uint4* c2, const uint4* c3,
                         float4* outp, int last) {
    int tid = threadIdx.x;
    int l8 = tid & 7;                       // feature octet-chunk 0..7
    int v = blockIdx.x * 32 + (tid >> 3);   // 32 nodes per 256-thread block
    if (v >= NN) return;
    float dv = dinv[v];
    int jb = rowptr[v], je = rowptr[v + 1];
    float4 aLo, aHi;
    {
        uint4 q = xw4[(size_t)v * 8 + l8];   // self loop
        float4 lo = bf4_to_f4(q.x, q.y), hi = bf4_to_f4(q.z, q.w);
        float s = dv * dv;
        aLo.x = s * lo.x; aLo.y = s * lo.y; aLo.z = s * lo.z; aLo.w = s * lo.w;
        aHi.x = s * hi.x; aHi.y = s * hi.y; aHi.z = s * hi.z; aHi.w = s * hi.w;
    }
#define WGT(E)  __half2float(__ushort_as_half((ushort)((E) >> 16)))
    for (int j = jb; j < je; j += 8) {
        uint e0 = csr[j];
        uint e1 = csr[min(j + 1, je - 1)];
        uint e2 = csr[min(j + 2, je - 1)];
        uint e3 = csr[min(j + 3, je - 1)];
        uint e4 = csr[min(j + 4, je - 1)];
        uint e5 = csr[min(j + 5, je - 1)];
        uint e6 = csr[min(j + 6, je - 1)];
        uint e7 = csr[min(j + 7, je - 1)];
        float w0 = WGT(e0);
        float w1 = (j + 1 < je) ? WGT(e1) : 0.f;
        float w2 = (j + 2 < je) ? WGT(e2) : 0.f;
        float w3 = (j + 3 < je) ? WGT(e3) : 0.f;
        float w4 = (j + 4 < je) ? WGT(e4) : 0.f;
        float w5 = (j + 5 < je) ? WGT(e5) : 0.f;
        float w6 = (j + 6 < je) ? WGT(e6) : 0.f;
        float w7 = (j + 7 < je) ? WGT(e7) : 0.f;
        uint4 q0 = xw4[(size_t)(e0 & 0xffffu) * 8 + l8];
        uint4 q1 = xw4[(size_t)(e1 & 0xffffu) * 8 + l8];
        uint4 q2 = xw4[(size_t)(e2 & 0xffffu) * 8 + l8];
        uint4 q3 = xw4[(size_t)(e3 & 0xffffu) * 8 + l8];
        uint4 q4 = xw4[(size_t)(e4 & 0xffffu) * 8 + l8];
        uint4 q5 = xw4[(size_t)(e5 & 0xffffu) * 8 + l8];
        uint4 q6 = xw4[(size_t)(e6 & 0xffffu) * 8 + l8];
        uint4 q7 = xw4[(size_t)(e7 & 0xffffu) * 8 + l8];
#define ACC(Q, W) { \
        float4 lo = bf4_to_f4(Q.x, Q.y), hi = bf4_to_f4(Q.z, Q.w); \
        aLo.x += W * lo.x; aLo.y += W * lo.y; aLo.z += W * lo.z; aLo.w += W * lo.w; \
        aHi.x += W * hi.x; aHi.y += W * hi.y; aHi.z += W * hi.z; aHi.w += W * hi.w; }
        ACC(q0, w0) ACC(q1, w1) ACC(q2, w2) ACC(q3, w3)
        ACC(q4, w4) ACC(q5, w5) ACC(q6, w6) ACC(q7, w7)
#undef ACC
    }
#undef WGT
    float4 bLo = bias4[2 * l8], bBhi = bias4[2 * l8 + 1];
    aLo.x += bLo.x; aLo.y += bLo.y; aLo.z += bLo.z; aLo.w += bLo.w;
    aHi.x += bBhi.x; aHi.y += bBhi.y; aHi.z += bBhi.z; aHi.w += bBhi.w;
    // LayerNorm over 64 features within the 8-lane octet
    float s = aLo.x + aLo.y + aLo.z + aLo.w + aHi.x + aHi.y + aHi.z + aHi.w;
#pragma unroll
    for (int o = 1; o <= 4; o <<= 1) s += __shfl_xor(s, o);
    float mu = s * (1.0f / 64.0f);
    float4 cLo = make_float4(aLo.x - mu, aLo.y - mu, aLo.z - mu, aLo.w - mu);
    float4 cHi = make_float4(aHi.x - mu, aHi.y - mu, aHi.z - mu, aHi.w - mu);
    float q2v = cLo.x * cLo.x + cLo.y * cLo.y + cLo.z * cLo.z + cLo.w * cLo.w
              + cHi.x * cHi.x + cHi.y * cHi.y + cHi.z * cHi.z + cHi.w * cHi.w;
#pragma unroll
    for (int o = 1; o <= 4; o <<= 1) q2v += __shfl_xor(q2v, o);
    float rs = rsqrtf(q2v * (1.0f / 64.0f) + 1e-5f);
    float4 gLo = gamma4[2 * l8], gHi = gamma4[2 * l8 + 1];
    float4 tLo = beta4[2 * l8],  tHi = beta4[2 * l8 + 1];
    float4 yLo = make_float4(cLo.x * rs * gLo.x + tLo.x, cLo.y * rs * gLo.y + tLo.y,
                             cLo.z * rs * gLo.z + tLo.z, cLo.w * rs * gLo.w + tLo.w);
    float4 yHi = make_float4(cHi.x * rs * gHi.x + tHi.x, cHi.y * rs * gHi.y + tHi.y,
                             cHi.z * rs * gHi.z + tHi.z, cHi.w * rs * gHi.w + tHi.w);
    float4 eLo = make_float4(yLo.x > 0.f ? yLo.x : 0.01f * yLo.x,
                             yLo.y > 0.f ? yLo.y : 0.01f * yLo.y,
                             yLo.z > 0.f ? yLo.z : 0.01f * yLo.z,
                             yLo.w > 0.f ? yLo.w : 0.01f * yLo.w);
    float4 eHi = make_float4(yHi.x > 0.f ? yHi.x : 0.01f * yHi.x,
                             yHi.y > 0.f ? yHi.y : 0.01f * yHi.y,
                             yHi.z > 0.f ? yHi.z : 0.01f * yHi.z,
                             yHi.w > 0.f ? yHi.w : 0.01f * yHi.w);
    if (!last) {
        uint4 o;
        o.x = (uint)f2bf(eLo.x) | ((uint)f2bf(eLo.y) << 16);
        o.y = (uint)f2bf(eLo.z) | ((uint)f2bf(eLo.w) << 16);
        o.z = (uint)f2bf(eHi.x) | ((uint)f2bf(eHi.y) << 16);
        o.w = (uint)f2bf(eHi.z) | ((uint)f2bf(eHi.w) << 16);
        next[(size_t)v * 8 + l8] = o;
    } else {
        uint4 u1 = c1[(size_t)v * 8 + l8];
        uint4 u2 = c2[(size_t)v * 8 + l8];
        uint4 u3 = c3[(size_t)v * 8 + l8];
        float4 p1 = bf4_to_f4(u1.x, u1.y), p1h = bf4_to_f4(u1.z, u1.w);
        float4 p2 = bf4_to_f4(u2.x, u2.y), p2h = bf4_to_f4(u2.z, u2.w);
        float4 p3 = bf4_to_f4(u3.x, u3.y), p3h = bf4_to_f4(u3.z, u3.w);
        float4 oLo, oHi;
        oLo.x = 0.5f * (p1.x + p2.x + p3.x + eLo.x);
        oLo.y = 0.5f * (p1.y + p2.y + p3.y + eLo.y);
        oLo.z = 0.5f * (p1.z + p2.z + p3.z + eLo.z);
        oLo.w = 0.5f * (p1.w + p2.w + p3.w + eLo.w);
        oHi.x = 0.5f * (p1h.x + p2h.x + p3h.x + eHi.x);
        oHi.y = 0.5f * (p1h.y + p2h.y + p3h.y + eHi.y);
        oHi.z = 0.5f * (p1h.z + p2h.z + p3h.z + eHi.z);
        oHi.w = 0.5f * (p1h.w + p2h.w + p3h.w + eHi.w);
        outp[(size_t)v * 16 + 2 * l8]     = oLo;
        outp[(size_t)v * 16 + 2 * l8 + 1] = oHi;
    }
}

// ---- launch -------------------------------------------------------------

extern "C" void kernel_launch(void* const* d_in, const int* in_sizes, int n_in,
                              void* d_out, int out_size, void* d_ws, size_t ws_size,
                              hipStream_t stream) {
    const float* x      = (const float*)d_in[0];
    const int*   ei     = (const int*)d_in[1];
    const int*   src    = ei;
    const int*   dst    = ei + NE;
    const int*   idx    = (const int*)d_in[2];
    const float* Ws     = (const float*)d_in[3];
    const float* bs     = (const float*)d_in[4];
    const float* gammas = (const float*)d_in[5];
    const float* betas  = (const float*)d_in[6];
    float* out = (float*)d_out;

    char* w = (char*)d_ws;
    auto alloc = [&](size_t bytes) -> char* {
        char* p = w;
        w += (bytes + 255) & ~(size_t)255;
        return p;
    };
    // cnt | c0 contiguous -> single zero-fill (csr is fully written, no zeroing)
    char*   zbase  = w;
    int*    cnt    = (int*)alloc((size_t)NN * 4);
    ushort* c0     = (ushort*)alloc((size_t)NN * 64 * 2);
    size_t  zbytes = (size_t)(w - zbase);
    ushort* c[NL];
    c[0] = c0;
    for (int l = 1; l < NL; ++l) c[l] = (ushort*)alloc((size_t)NN * 64 * 2);
    ushort* xw     = (ushort*)alloc((size_t)NN * 64 * 2);
    int*    rowptr = (int*)alloc((size_t)(NN + 1) * 4);
    int*    rank   = (int*)alloc((size_t)NE * 4);
    float*  dinv   = (float*)alloc((size_t)NN * 4);
    int*    bsum   = (int*)alloc(64 * 4);
    uint*   csr    = (uint*)alloc((size_t)NE * 4);

    hipMemsetAsync(zbase, 0, zbytes, stream);

    count_edges_k<<<(NE + 255) / 256, 256, 0, stream>>>(dst, cnt, rank, NE);
    int nb = (NN + 1023) / 1024;   // 49
    scan_local_k<<<nb, 1024, 0, stream>>>(cnt, rowptr, bsum, NN);
    finalize_k<<<nb, 1024, 0, stream>>>(rowptr, bsum, cnt, dinv, NN, nb);
    fill_scatter_k<<<3125 + 1563, 256, 0, stream>>>(src, dst, rank, rowptr, dinv, csr,
                                                    (const float4*)x, idx, (ushort4*)c[0]);

    int agrid = (NN + 31) / 32;   // 1563
    for (int l = 0; l < NL; ++l) {
        gemm64_k<<<NN / 16, 256, 0, stream>>>((const uint2*)c[l], Ws + (size_t)l * 64 * 64,
                                              xw);
        int last = (l == NL - 1);
        agg_ln_k<<<agrid, 256, 0, stream>>>((const uint4*)xw, rowptr, csr, dinv,
                                            (const float4*)(bs + l * 64),
                                            (const float4*)(gammas + l * 64),
                                            (const float4*)(betas + l * 64),
                                            last ? nullptr : (uint4*)c[l + 1],
                                            (const uint4*)c[1], (const uint4*)c[2],
                                            (const uint4*)c[3], (float4*)out, last);
    }
}

// Round 14
// 170.037 us; speedup vs baseline: 1.9993x; 1.1762x over previous
//
#include <hip/hip_runtime.h>
#include <hip/hip_fp16.h>

#define NN 50000
#define NP 25000
#define NE 800000
#define DD 64
#define NL 4

// ---- helpers ------------------------------------------------------------

__device__ __forceinline__ ushort f2bf(float f) {
    unsigned u = __float_as_uint(f);
    unsigned r = (u + 0x7fffu + ((u >> 16) & 1u)) >> 16;   // RNE
    return (ushort)r;
}

__device__ __forceinline__ float4 bf4_to_f4(uint a, uint b) {
    float4 r;
    r.x = __uint_as_float(a << 16);
    r.y = __uint_as_float(a & 0xffff0000u);
    r.z = __uint_as_float(b << 16);
    r.w = __uint_as_float(b & 0xffff0000u);
    return r;
}

// ---- CSR build ----------------------------------------------------------

__global__ void count_edges_k(const int* __restrict__ dst, int* __restrict__ cnt,
                              int* __restrict__ rank, int E) {
    int e = blockIdx.x * 256 + threadIdx.x;
    if (e < E) rank[e] = atomicAdd(&cnt[dst[e]], 1);
}

__global__ void scan_local_k(const int* __restrict__ cnt, int* __restrict__ rowptr,
                             int* __restrict__ bsum, int n) {
    __shared__ int tmp[1024];
    int t = threadIdx.x;
    int i = blockIdx.x * 1024 + t;
    int v = (i < n) ? cnt[i] : 0;
    tmp[t] = v;
    __syncthreads();
    for (int off = 1; off < 1024; off <<= 1) {
        int a = (t >= off) ? tmp[t - off] : 0;
        __syncthreads();
        tmp[t] += a;
        __syncthreads();
    }
    if (i < n) rowptr[i] = tmp[t] - v;      // block-local exclusive scan
    if (t == 1023) bsum[blockIdx.x] = tmp[1023];
}

// Finalize: each block redundantly wave-scans the 49 raw block sums (cheap),
// adds its base, computes dinv. No separate scan_sums dispatch.
__global__ void finalize_k(int* __restrict__ rowptr, const int* __restrict__ bsum,
                           const int* __restrict__ cnt, float* __restrict__ dinv,
                           int n, int nb) {
    __shared__ int base_sh, total_sh;
    int t = threadIdx.x;
    if (t < 64) {
        int v = (t < nb) ? bsum[t] : 0;
        int s = v;
#pragma unroll
        for (int o = 1; o < 64; o <<= 1) {
            int u = __shfl_up(s, o);
            if (t >= o) s += u;
        }
        if (t == (int)blockIdx.x) base_sh = s - v;
        if (t == nb - 1) total_sh = s;
    }
    __syncthreads();
    int i = blockIdx.x * 1024 + t;
    if (i < n) {
        rowptr[i] += base_sh;
        dinv[i] = rsqrtf((float)(cnt[i] + 1));   // +1 self loop
    }
    if (i == n) rowptr[n] = total_sh;
}

// csr entry: bits 0..15 = src index, bits 16..31 = fp16 weight.
__global__ void fill_scatter_k(const int* __restrict__ src, const int* __restrict__ dst,
                               const int* __restrict__ rank, const int* __restrict__ rowptr,
                               const float* __restrict__ dinv, uint* __restrict__ csr,
                               const float4* __restrict__ x4, const int* __restrict__ idx,
                               ushort4* __restrict__ c0) {
    int b = blockIdx.x;
    if (b < 3125) {
        int e = b * 256 + threadIdx.x;   // 3125*256 == NE
        int s = src[e], d = dst[e];
        int p = rowptr[d] + rank[e];
        float w = dinv[s] * dinv[d];
        uint h = (uint)__half_as_ushort(__float2half_rn(w));
        csr[p] = (uint)s | (h << 16);
    } else {
        int i = (b - 3125) * 256 + threadIdx.x;   // NP*16 quads
        if (i >= NP * 16) return;
        int row = i >> 4, q = i & 15;
        float4 v = x4[i];
        ushort4 o;
        o.x = f2bf(v.x); o.y = f2bf(v.y); o.z = f2bf(v.z); o.w = f2bf(v.w);
        c0[(size_t)idx[row] * 16 + q] = o;
    }
}

// ---- fused layer: z = A_hat*cur (gather) -> LDS; y = z@W + b; LN; act ---
// Phase 1 (R7-proven gather): 8-lane octet per node, 8-deep clamped unroll,
// 64 row-gathers in flight per wave; accumulates z in f32, stores to LDS.
// Phase 2 (R11-proven gemm loop): same thread keeps node t>>3, cols (t&7)*8;
// W staged once in LDS; z read broadcast, conflict-free. LN intra-octet.
// Removes the separate gemm dispatch and the xw bf16 round-trip.

__global__ void agg_mm_ln_k(const uint4* __restrict__ cur4, const int* __restrict__ rowptr,
                            const uint* __restrict__ csr, const float* __restrict__ dinv,
                            const float* __restrict__ W,
                            const float4* __restrict__ bias4,
                            const float4* __restrict__ gamma4,
                            const float4* __restrict__ beta4, uint4* next,
                            const uint4* c1, const uint4* c2, const uint4* c3,
                            float4* outp, int last) {
    __shared__ float sW[64][64];    // 16 KB
    __shared__ float sz[32][68];    // 8.7 KB, 68-pad: f4-aligned, conflict-free
    int t = threadIdx.x;            // 256 threads = 32 nodes
    {   // stage W (overlaps with gather issue below)
        const float4* W4 = (const float4*)W;
        float4* sW4 = (float4*)sW;
#pragma unroll
        for (int j = 0; j < 4; ++j) sW4[t + 256 * j] = W4[t + 256 * j];
    }
    int l8 = t & 7;                      // feature octet-chunk 0..7
    int oct = t >> 3;                    // node within block 0..31
    int v = blockIdx.x * 32 + oct;
    float4 aLo = make_float4(0.f, 0.f, 0.f, 0.f);
    float4 aHi = make_float4(0.f, 0.f, 0.f, 0.f);
    if (v < NN) {
        float dv = dinv[v];
        int jb = rowptr[v], je = rowptr[v + 1];
        {
            uint4 q = cur4[(size_t)v * 8 + l8];   // self loop
            float4 lo = bf4_to_f4(q.x, q.y), hi = bf4_to_f4(q.z, q.w);
            float s = dv * dv;
            aLo.x = s * lo.x; aLo.y = s * lo.y; aLo.z = s * lo.z; aLo.w = s * lo.w;
            aHi.x = s * hi.x; aHi.y = s * hi.y; aHi.z = s * hi.z; aHi.w = s * hi.w;
        }
#define WGT(E)  __half2float(__ushort_as_half((ushort)((E) >> 16)))
        for (int j = jb; j < je; j += 8) {
            uint e0 = csr[j];
            uint e1 = csr[min(j + 1, je - 1)];
            uint e2 = csr[min(j + 2, je - 1)];
            uint e3 = csr[min(j + 3, je - 1)];
            uint e4 = csr[min(j + 4, je - 1)];
            uint e5 = csr[min(j + 5, je - 1)];
            uint e6 = csr[min(j + 6, je - 1)];
            uint e7 = csr[min(j + 7, je - 1)];
            float w0 = WGT(e0);
            float w1 = (j + 1 < je) ? WGT(e1) : 0.f;
            float w2 = (j + 2 < je) ? WGT(e2) : 0.f;
            float w3 = (j + 3 < je) ? WGT(e3) : 0.f;
            float w4 = (j + 4 < je) ? WGT(e4) : 0.f;
            float w5 = (j + 5 < je) ? WGT(e5) : 0.f;
            float w6 = (j + 6 < je) ? WGT(e6) : 0.f;
            float w7 = (j + 7 < je) ? WGT(e7) : 0.f;
            uint4 q0 = cur4[(size_t)(e0 & 0xffffu) * 8 + l8];
            uint4 q1 = cur4[(size_t)(e1 & 0xffffu) * 8 + l8];
            uint4 q2 = cur4[(size_t)(e2 & 0xffffu) * 8 + l8];
            uint4 q3 = cur4[(size_t)(e3 & 0xffffu) * 8 + l8];
            uint4 q4 = cur4[(size_t)(e4 & 0xffffu) * 8 + l8];
            uint4 q5 = cur4[(size_t)(e5 & 0xffffu) * 8 + l8];
            uint4 q6 = cur4[(size_t)(e6 & 0xffffu) * 8 + l8];
            uint4 q7 = cur4[(size_t)(e7 & 0xffffu) * 8 + l8];
#define ACC(Q, Wt) { \
            float4 lo = bf4_to_f4(Q.x, Q.y), hi = bf4_to_f4(Q.z, Q.w); \
            aLo.x += Wt * lo.x; aLo.y += Wt * lo.y; aLo.z += Wt * lo.z; aLo.w += Wt * lo.w; \
            aHi.x += Wt * hi.x; aHi.y += Wt * hi.y; aHi.z += Wt * hi.z; aHi.w += Wt * hi.w; }
            ACC(q0, w0) ACC(q1, w1) ACC(q2, w2) ACC(q3, w3)
            ACC(q4, w4) ACC(q5, w5) ACC(q6, w6) ACC(q7, w7)
#undef ACC
        }
#undef WGT
    }
    *(float4*)&sz[oct][8 * l8]     = aLo;
    *(float4*)&sz[oct][8 * l8 + 4] = aHi;
    __syncthreads();
    // ---- phase 2: y[c8..c8+7] = sum_k z[oct][k] * W[k][c8..c8+7] ----
    int c8 = 8 * l8;
    float4 y1 = make_float4(0.f, 0.f, 0.f, 0.f);
    float4 y2 = make_float4(0.f, 0.f, 0.f, 0.f);
#pragma unroll
    for (int k = 0; k < 64; ++k) {
        float a = sz[oct][k];
        float4 w1 = *(const float4*)&sW[k][c8];
        float4 w2 = *(const float4*)&sW[k][c8 + 4];
        y1.x += a * w1.x; y1.y += a * w1.y; y1.z += a * w1.z; y1.w += a * w1.w;
        y2.x += a * w2.x; y2.y += a * w2.y; y2.z += a * w2.z; y2.w += a * w2.w;
    }
    if (v >= NN) return;
    float4 bLo = bias4[2 * l8], bHi = bias4[2 * l8 + 1];
    y1.x += bLo.x; y1.y += bLo.y; y1.z += bLo.z; y1.w += bLo.w;
    y2.x += bHi.x; y2.y += bHi.y; y2.z += bHi.z; y2.w += bHi.w;
    // LayerNorm over 64 features within the 8-lane octet
    float s = y1.x + y1.y + y1.z + y1.w + y2.x + y2.y + y2.z + y2.w;
#pragma unroll
    for (int o = 1; o <= 4; o <<= 1) s += __shfl_xor(s, o);
    float mu = s * (1.0f / 64.0f);
    float4 cLo = make_float4(y1.x - mu, y1.y - mu, y1.z - mu, y1.w - mu);
    float4 cHi = make_float4(y2.x - mu, y2.y - mu, y2.z - mu, y2.w - mu);
    float q2v = cLo.x * cLo.x + cLo.y * cLo.y + cLo.z * cLo.z + cLo.w * cLo.w
              + cHi.x * cHi.x + cHi.y * cHi.y + cHi.z * cHi.z + cHi.w * cHi.w;
#pragma unroll
    for (int o = 1; o <= 4; o <<= 1) q2v += __shfl_xor(q2v, o);
    float rs = rsqrtf(q2v * (1.0f / 64.0f) + 1e-5f);
    float4 gLo = gamma4[2 * l8], gHi = gamma4[2 * l8 + 1];
    float4 tLo = beta4[2 * l8],  tHi = beta4[2 * l8 + 1];
    float4 yLo = make_float4(cLo.x * rs * gLo.x + tLo.x, cLo.y * rs * gLo.y + tLo.y,
                             cLo.z * rs * gLo.z + tLo.z, cLo.w * rs * gLo.w + tLo.w);
    float4 yHi = make_float4(cHi.x * rs * gHi.x + tHi.x, cHi.y * rs * gHi.y + tHi.y,
                             cHi.z * rs * gHi.z + tHi.z, cHi.w * rs * gHi.w + tHi.w);
    float4 eLo = make_float4(yLo.x > 0.f ? yLo.x : 0.01f * yLo.x,
                             yLo.y > 0.f ? yLo.y : 0.01f * yLo.y,
                             yLo.z > 0.f ? yLo.z : 0.01f * yLo.z,
                             yLo.w > 0.f ? yLo.w : 0.01f * yLo.w);
    float4 eHi = make_float4(yHi.x > 0.f ? yHi.x : 0.01f * yHi.x,
                             yHi.y > 0.f ? yHi.y : 0.01f * yHi.y,
                             yHi.z > 0.f ? yHi.z : 0.01f * yHi.z,
                             yHi.w > 0.f ? yHi.w : 0.01f * yHi.w);
    if (!last) {
        uint4 o;
        o.x = (uint)f2bf(eLo.x) | ((uint)f2bf(eLo.y) << 16);
        o.y = (uint)f2bf(eLo.z) | ((uint)f2bf(eLo.w) << 16);
        o.z = (uint)f2bf(eHi.x) | ((uint)f2bf(eHi.y) << 16);
        o.w = (uint)f2bf(eHi.z) | ((uint)f2bf(eHi.w) << 16);
        next[(size_t)v * 8 + l8] = o;
    } else {
        uint4 u1 = c1[(size_t)v * 8 + l8];
        uint4 u2 = c2[(size_t)v * 8 + l8];
        uint4 u3 = c3[(size_t)v * 8 + l8];
        float4 p1 = bf4_to_f4(u1.x, u1.y), p1h = bf4_to_f4(u1.z, u1.w);
        float4 p2 = bf4_to_f4(u2.x, u2.y), p2h = bf4_to_f4(u2.z, u2.w);
        float4 p3 = bf4_to_f4(u3.x, u3.y), p3h = bf4_to_f4(u3.z, u3.w);
        float4 oLo, oHi;
        oLo.x = 0.5f * (p1.x + p2.x + p3.x + eLo.x);
        oLo.y = 0.5f * (p1.y + p2.y + p3.y + eLo.y);
        oLo.z = 0.5f * (p1.z + p2.z + p3.z + eLo.z);
        oLo.w = 0.5f * (p1.w + p2.w + p3.w + eLo.w);
        oHi.x = 0.5f * (p1h.x + p2h.x + p3h.x + eHi.x);
        oHi.y = 0.5f * (p1h.y + p2h.y + p3h.y + eHi.y);
        oHi.z = 0.5f * (p1h.z + p2h.z + p3h.z + eHi.z);
        oHi.w = 0.5f * (p1h.w + p2h.w + p3h.w + eHi.w);
        outp[(size_t)v * 16 + 2 * l8]     = oLo;
        outp[(size_t)v * 16 + 2 * l8 + 1] = oHi;
    }
}

// ---- launch -------------------------------------------------------------

extern "C" void kernel_launch(void* const* d_in, const int* in_sizes, int n_in,
                              void* d_out, int out_size, void* d_ws, size_t ws_size,
                              hipStream_t stream) {
    const float* x      = (const float*)d_in[0];
    const int*   ei     = (const int*)d_in[1];
    const int*   src    = ei;
    const int*   dst    = ei + NE;
    const int*   idx    = (const int*)d_in[2];
    const float* Ws     = (const float*)d_in[3];
    const float* bs     = (const float*)d_in[4];
    const float* gammas = (const float*)d_in[5];
    const float* betas  = (const float*)d_in[6];
    float* out = (float*)d_out;

    char* w = (char*)d_ws;
    auto alloc = [&](size_t bytes) -> char* {
        char* p = w;
        w += (bytes + 255) & ~(size_t)255;
        return p;
    };
    // cnt | c0 contiguous -> single zero-fill (csr fully written, no zeroing)
    char*   zbase  = w;
    int*    cnt    = (int*)alloc((size_t)NN * 4);
    ushort* c0     = (ushort*)alloc((size_t)NN * 64 * 2);
    size_t  zbytes = (size_t)(w - zbase);
    ushort* c[NL + 1];
    c[0] = c0;
    for (int l = 1; l <= NL; ++l) c[l] = (ushort*)alloc((size_t)NN * 64 * 2);
    int*    rowptr = (int*)alloc((size_t)(NN + 1) * 4);
    int*    rank   = (int*)alloc((size_t)NE * 4);
    float*  dinv   = (float*)alloc((size_t)NN * 4);
    int*    bsum   = (int*)alloc(64 * 4);
    uint*   csr    = (uint*)alloc((size_t)NE * 4);

    hipMemsetAsync(zbase, 0, zbytes, stream);

    count_edges_k<<<(NE + 255) / 256, 256, 0, stream>>>(dst, cnt, rank, NE);
    int nb = (NN + 1023) / 1024;   // 49
    scan_local_k<<<nb, 1024, 0, stream>>>(cnt, rowptr, bsum, NN);
    finalize_k<<<nb, 1024, 0, stream>>>(rowptr, bsum, cnt, dinv, NN, nb);
    fill_scatter_k<<<3125 + 1563, 256, 0, stream>>>(src, dst, rank, rowptr, dinv, csr,
                                                    (const float4*)x, idx, (ushort4*)c[0]);

    int agrid = (NN + 31) / 32;   // 1563
    for (int l = 0; l < NL; ++l) {
        int last = (l == NL - 1);
        agg_mm_ln_k<<<agrid, 256, 0, stream>>>((const uint4*)c[l], rowptr, csr, dinv,
                                               Ws + (size_t)l * 64 * 64,
                                               (const float4*)(bs + l * 64),
                                               (const float4*)(gammas + l * 64),
                                               (const float4*)(betas + l * 64),
                                               last ? nullptr : (uint4*)c[l + 1],
                                               (const uint4*)c[1], (const uint4*)c[2],
                                               (const uint4*)c[3], (float4*)out, last);
    }
}